// Round 4
// baseline (430.999 us; speedup 1.0000x reference)
//
#include <hip/hip_runtime.h>
#include <stdint.h>

// NeighborAttention fused kernel, MI355X gfx950 — round 4: pinned prefetch +
// wave-local subtile dataflow.
// B=4,N=4096,K=32,C=128,H=4,d=32. One block = 16 nodes, 256 threads (4 waves),
// grid = 1024. E streamed in 4 subtiles (128x128). Wave w owns node w of each
// subtile: scores MFMA -> in-register shfl softmax -> HV MFMA reusing the SAME
// E A-fragments, attn broadcast via wave-private LDS row (no block barrier).
// E prefetch pinned with sched_barrier(0) (r3's loads were compiler-sunk,
// VGPR=84 proved it). 2 barriers/subtile; staging overlaps compute.
// All gemms on MFMA. LDS ~73.5 KB -> 2 blocks/CU. dtype detected in-kernel.

typedef __attribute__((ext_vector_type(8))) short short8;   // 8 bf16 = 16 B
typedef __attribute__((ext_vector_type(4))) float f32x4;

#define NPB   16
#define CDIM  128
#define KN    32
#define ESTR  136   // sE row stride (bf16 units)
#define TSTR  136   // sT row stride
#define QSTR  136   // sQ row stride
#define CATS  392   // sCat row stride (bf16 units), 384 data + pad
#define SSTR  36    // sS row stride (fp32 units), 32 attn + [33]=1/asum

__device__ __forceinline__ float bf2f(short s) {
    union { unsigned int u; float f; } v;
    v.u = ((unsigned int)(unsigned short)s) << 16;
    return v.f;
}
__device__ __forceinline__ short f2bf(float f) {
    union { float ff; unsigned int u; } v; v.ff = f;
    unsigned int u = v.u;
    u += 0x7FFFu + ((u >> 16) & 1u);   // round-to-nearest-even
    return (short)(u >> 16);
}

template<bool FP32>
__device__ __forceinline__ short8 load8bf(const void* p, size_t idx) {
    if constexpr (FP32) {
        const float* fp = (const float*)p + idx;
        f32x4 a = *(const f32x4*)fp;
        f32x4 b = *(const f32x4*)(fp + 4);
        short8 r;
        r[0] = f2bf(a[0]); r[1] = f2bf(a[1]); r[2] = f2bf(a[2]); r[3] = f2bf(a[3]);
        r[4] = f2bf(b[0]); r[5] = f2bf(b[1]); r[6] = f2bf(b[2]); r[7] = f2bf(b[3]);
        return r;
    } else {
        return *(const short8*)((const short*)p + idx);
    }
}

template<bool FP32>
__device__ __forceinline__ short loadbf1(const void* p, size_t idx) {
    if constexpr (FP32) return f2bf(((const float*)p)[idx]);
    else return ((const short*)p)[idx];
}

struct alignas(16) Smem {
    short sE[128 * ESTR];     // 34816 B  E subtile (bf16)
    short sT[64 * TSTR];      // 17408 B  t = (q·Wk)*scale (bf16) [nh][ci]
    short sQ[16 * QSTR];      //  4352 B  q rows (bf16)
    short sCat[16 * CATS];    // 12544 B  [mean|sum|max] per node (bf16)
    float sS[16 * SSTR];      //  2304 B  attn rows, wave-private (+[33]=ainv)
    int   sMask[NPB * KN];    //  2048 B
};                            // 73472 B -> 2 blocks/CU

template<bool FP32>
__device__ __forceinline__ void issueE(const void* hE, size_t base, int tid,
                                       f32x4 (&eF)[8][2], short8 (&eB)[8]) {
    if constexpr (FP32) {
        #pragma unroll
        for (int it = 0; it < 8; ++it) {
            const float* p = (const float*)hE + base + (size_t)(it * 256 + tid) * 8;
            eF[it][0] = *(const f32x4*)p;
            eF[it][1] = *(const f32x4*)(p + 4);
        }
    } else {
        #pragma unroll
        for (int it = 0; it < 8; ++it)
            eB[it] = *(const short8*)((const short*)hE + base + (size_t)(it * 256 + tid) * 8);
    }
    // Pin: loads must not be sunk below this point (r3: compiler sank them).
    __builtin_amdgcn_sched_barrier(0);
}

template<bool FP32>
__device__ __forceinline__ void writeE(short* sE, int tid,
                                       const f32x4 (&eF)[8][2], const short8 (&eB)[8]) {
    #pragma unroll
    for (int it = 0; it < 8; ++it) {
        const int chunk = it * 256 + tid, row = chunk >> 4, cc = chunk & 15;
        short8 v;
        if constexpr (FP32) {
            #pragma unroll
            for (int t = 0; t < 4; ++t) { v[t] = f2bf(eF[it][0][t]); v[4 + t] = f2bf(eF[it][1][t]); }
        } else v = eB[it];
        *(short8*)&sE[row * ESTR + cc * 8] = v;
    }
}

template<bool FP32>
__device__ __forceinline__ void na_body(Smem& sm,
    const void* __restrict__ hX, const void* __restrict__ hE,
    const int* __restrict__ mask, const void* __restrict__ WQ,
    const void* __restrict__ WK, const void* __restrict__ WV,
    const void* __restrict__ WO, void* __restrict__ out)
{
    const int tid  = threadIdx.x;
    const int lane = tid & 63;
    const int w    = tid >> 6;      // wave 0..3 == node-local owner
    const int quad = lane >> 4;
    const int l15  = lane & 15;
    const int nb   = blockIdx.x * NPB;
    const size_t ebase = (size_t)nb * (KN * CDIM);

    // ---- issue E subtile-0 prefetch first (longest latency) ----
    f32x4 eF[8][2]; short8 eB[8];
    issueE<FP32>(hE, ebase, tid, eF, eB);

    // ---- stage mask (coalesced, 2 ints/thread) ----
    *(int2*)&sm.sMask[tid * 2] = *(const int2*)&mask[(size_t)nb * KN + tid * 2];

    // ---- X A-frags: row l15 = node ----
    short8 ax[4];
    #pragma unroll
    for (int kk = 0; kk < 4; ++kk)
        ax[kk] = load8bf<FP32>(hX, (size_t)(nb + l15) * CDIM + kk * 32 + quad * 8);

    // ---- WQ B-frags ----
    short8 bq[2][4];
    #pragma unroll
    for (int t2 = 0; t2 < 2; ++t2)
        #pragma unroll
        for (int kk = 0; kk < 4; ++kk)
            bq[t2][kk] = load8bf<FP32>(WQ, (size_t)(w * 32 + t2 * 16 + l15) * CDIM + kk * 32 + quad * 8);

    // ---- WK B-frags for t-gemm (scalar gather, once) ----
    short8 bk[2][4];
    #pragma unroll
    for (int t2 = 0; t2 < 2; ++t2)
        #pragma unroll
        for (int kk = 0; kk < 4; ++kk) {
            const int j = w * 32 + t2 * 16 + l15;
            short8 b;
            #pragma unroll
            for (int jj = 0; jj < 8; ++jj)
                b[jj] = loadbf1<FP32>(WK, (size_t)(kk * 32 + quad * 8 + jj) * CDIM + j);
            bk[t2][kk] = b;
        }

    // ---- q = X @ WQ^T via MFMA -> sQ (bf16) ----
    {
        f32x4 o0 = {0.f,0.f,0.f,0.f}, o1 = {0.f,0.f,0.f,0.f};
        #pragma unroll
        for (int kk = 0; kk < 4; ++kk) {
            o0 = __builtin_amdgcn_mfma_f32_16x16x32_bf16(ax[kk], bq[0][kk], o0, 0, 0, 0);
            o1 = __builtin_amdgcn_mfma_f32_16x16x32_bf16(ax[kk], bq[1][kk], o1, 0, 0, 0);
        }
        #pragma unroll
        for (int r = 0; r < 4; ++r) {
            const int n = quad * 4 + r;                       // C row = node
            sm.sQ[n * QSTR + w * 32 + l15]      = f2bf(o0[r]);
            sm.sQ[n * QSTR + w * 32 + 16 + l15] = f2bf(o1[r]);
        }
    }
    __syncthreads();   // B1: sQ + sMask ready

    // ---- t = (q · WK)*scale via masked-head MFMA -> sT (bf16) ----
    {
        const float scale = 0.17677669529663687f;   // 1/sqrt(32)
        const short8 zz = {0,0,0,0,0,0,0,0};
        #pragma unroll
        for (int m = 0; m < 4; ++m) {
            const int n_g = m * 4 + (l15 >> 2), h_ = l15 & 3;
            const short8 qv = *(const short8*)&sm.sQ[n_g * QSTR + h_ * 32 + quad * 8];
            f32x4 c0 = {0.f,0.f,0.f,0.f}, c1 = {0.f,0.f,0.f,0.f};
            #pragma unroll
            for (int kk = 0; kk < 4; ++kk) {
                const short8 af = (kk == h_) ? qv : zz;
                c0 = __builtin_amdgcn_mfma_f32_16x16x32_bf16(af, bk[0][kk], c0, 0, 0, 0);
                c1 = __builtin_amdgcn_mfma_f32_16x16x32_bf16(af, bk[1][kk], c1, 0, 0, 0);
            }
            #pragma unroll
            for (int r = 0; r < 4; ++r) {
                const int row = m * 16 + quad * 4 + r;        // (n,h) row
                sm.sT[row * TSTR + w * 32 + l15]      = f2bf(c0[r] * scale);
                sm.sT[row * TSTR + w * 32 + 16 + l15] = f2bf(c1[r] * scale);
            }
        }
    }

    // ---- write E0 to sE; issue E1 (pinned) ----
    writeE<FP32>(sm.sE, tid, eF, eB);
    issueE<FP32>(hE, ebase + 1 * 128 * 128, tid, eF, eB);
    __syncthreads();   // B2: sT + sE(0) ready

    // ================= subtile loop (4 nodes each; wave w owns node w) =====
    #pragma unroll 1
    for (int s = 0; s < 4; ++s) {
        // ---- frag loads from sE/sT (only LDS use of this subtile) ----
        short8 bs[4], a0[4], a1[4];
        #pragma unroll
        for (int kk = 0; kk < 4; ++kk) {
            bs[kk] = *(const short8*)&sm.sT[(16 * s + l15) * TSTR + kk * 32 + quad * 8];
            a0[kk] = *(const short8*)&sm.sE[(w * 32 + l15) * ESTR + kk * 32 + quad * 8];
            a1[kk] = *(const short8*)&sm.sE[(w * 32 + 16 + l15) * ESTR + kk * 32 + quad * 8];
        }
        if (s < 3) {
            __syncthreads();                    // all waves' sE reads done
            writeE<FP32>(sm.sE, tid, eF, eB);   // sE := E[s+1], overlaps compute
            if (s < 2) issueE<FP32>(hE, ebase + (size_t)(s + 2) * 128 * 128, tid, eF, eB);
        }

        // ---- P4: scores for node w (cols l15=(n,h); keep n==w) ----
        f32x4 s0 = {0.f,0.f,0.f,0.f}, s1 = {0.f,0.f,0.f,0.f};
        #pragma unroll
        for (int kk = 0; kk < 4; ++kk) {
            s0 = __builtin_amdgcn_mfma_f32_16x16x32_bf16(a0[kk], bs[kk], s0, 0, 0, 0);
            s1 = __builtin_amdgcn_mfma_f32_16x16x32_bf16(a1[kk], bs[kk], s1, 0, 0, 0);
        }

        // ---- in-register masked softmax (per column, across quads) ----
        {
            const int* mp = &sm.sMask[(s * 4 + (l15 >> 2)) * KN];
            float x[8]; int mk[8];
            #pragma unroll
            for (int j = 0; j < 4; ++j) {
                x[j] = s0[j];     mk[j]     = mp[quad * 4 + j];
                x[4 + j] = s1[j]; mk[4 + j] = mp[16 + quad * 4 + j];
            }
            float m = -3.0e38f;
            #pragma unroll
            for (int j = 0; j < 8; ++j) m = fmaxf(m, (mk[j] > 0) ? x[j] : -3.0e38f);
            m = fmaxf(m, __shfl_xor(m, 16));
            m = fmaxf(m, __shfl_xor(m, 32));
            float dsum = 0.f;
            #pragma unroll
            for (int j = 0; j < 8; ++j) {
                const float e = __expf(fminf(x[j] - m, 0.f)) * ((mk[j] > 0) ? 1.f : 0.f);
                x[j] = e; dsum += e;
            }
            dsum += __shfl_xor(dsum, 16);
            dsum += __shfl_xor(dsum, 32);
            const float inv = (dsum > 0.f) ? (1.f / dsum) : 0.f;
            if ((l15 >> 2) == w) {              // owner lanes broadcast attn
                float* sp = &sm.sS[(w * 4 + (l15 & 3)) * SSTR];
                #pragma unroll
                for (int j = 0; j < 4; ++j) {
                    sp[quad * 4 + j]      = x[j] * inv;
                    sp[16 + quad * 4 + j] = x[4 + j] * inv;
                }
                if (quad == 0)
                    sp[33] = 1.0f / (((dsum > 0.f) ? 1.0f : 0.0f) + 1e-8f);
            }
        }
        // wave-private LDS: reads below are same-wave, lgkmcnt-ordered only

        // ---- P6: HV for node w, all 8 col-tiles; reuse aE frags ----
        #pragma unroll
        for (int ct = 0; ct < 8; ++ct) {
            const int h = ct >> 1;
            f32x4 av0 = {0.f,0.f,0.f,0.f}, av1 = {0.f,0.f,0.f,0.f};
            #pragma unroll
            for (int kk = 0; kk < 4; ++kk) {
                const short8 bvf = load8bf<FP32>(WV, (size_t)(ct * 16 + l15) * CDIM + kk * 32 + quad * 8);
                av0 = __builtin_amdgcn_mfma_f32_16x16x32_bf16(a0[kk], bvf, av0, 0, 0, 0);
                av1 = __builtin_amdgcn_mfma_f32_16x16x32_bf16(a1[kk], bvf, av1, 0, 0, 0);
            }
            const float* ap = &sm.sS[(w * 4 + h) * SSTR];
            const float ainv = ap[33];
            float sum = 0.f, mx = -3.0e38f;
            #pragma unroll
            for (int r = 0; r < 4; ++r) {
                const float p0 = ap[quad * 4 + r]      * av0[r];
                const float p1 = ap[16 + quad * 4 + r] * av1[r];
                sum += p0 + p1;
                mx = fmaxf(mx, fmaxf(p0, p1));
            }
            sum += __shfl_xor(sum, 16);
            sum += __shfl_xor(sum, 32);
            mx = fmaxf(mx, __shfl_xor(mx, 16));
            mx = fmaxf(mx, __shfl_xor(mx, 32));
            if (quad == 0) {
                const int c = ct * 16 + l15, row = s * 4 + w;
                sm.sCat[row * CATS + c]       = f2bf(sum * ainv);  // mean
                sm.sCat[row * CATS + 128 + c] = f2bf(sum);         // sum
                sm.sCat[row * CATS + 256 + c] = f2bf(mx);          // max
            }
        }

        if (s < 3) __syncthreads();   // sE[s+1] staged -> next iter may read
    }
    __syncthreads();   // all sCat rows visible

    // ---- P7: out = cat @ WO^T via MFMA (M=16, K=384, wave owns 32 cols) ----
    {
        f32x4 o0 = {0.f,0.f,0.f,0.f}, o1 = {0.f,0.f,0.f,0.f};
        #pragma unroll
        for (int kk = 0; kk < 12; ++kk) {
            const short8 a  = *(const short8*)&sm.sCat[l15 * CATS + kk * 32 + quad * 8];
            const short8 b0 = load8bf<FP32>(WO, (size_t)(w * 32 + l15) * 384 + kk * 32 + quad * 8);
            const short8 b1 = load8bf<FP32>(WO, (size_t)(w * 32 + 16 + l15) * 384 + kk * 32 + quad * 8);
            o0 = __builtin_amdgcn_mfma_f32_16x16x32_bf16(a, b0, o0, 0, 0, 0);
            o1 = __builtin_amdgcn_mfma_f32_16x16x32_bf16(a, b1, o1, 0, 0, 0);
        }
        #pragma unroll
        for (int r = 0; r < 4; ++r) {
            const int node = quad * 4 + r;
            const size_t base = (size_t)(nb + node) * CDIM + w * 32;
            if constexpr (FP32) {
                ((float*)out)[base + l15]      = o0[r];
                ((float*)out)[base + 16 + l15] = o1[r];
            } else {
                ((short*)out)[base + l15]      = f2bf(o0[r]);
                ((short*)out)[base + 16 + l15] = f2bf(o1[r]);
            }
        }
    }
}

__global__ __launch_bounds__(256, 2)
void na_fused(const void* __restrict__ hX, const void* __restrict__ hE,
              const int* __restrict__ mask, const void* __restrict__ WQ,
              const void* __restrict__ WK, const void* __restrict__ WV,
              const void* __restrict__ WO, void* __restrict__ out)
{
    __shared__ Smem sm;
    // in-kernel dtype detect on WQ[0..511]: fp32 low halves decode to wild bf16s
    const short* wq16 = (const short*)WQ;
    const int lane = threadIdx.x & 63;
    int cnt = 0;
    #pragma unroll
    for (int i = 0; i < 8; ++i) {
        const float v = bf2f(wq16[lane + i * 64]);
        if (!(fabsf(v) < 8.0f)) cnt++;
    }
    #pragma unroll
    for (int d = 1; d < 64; d <<= 1) cnt += __shfl_xor(cnt, d);
    if (cnt > 16) na_body<true >(sm, hX, hE, mask, WQ, WK, WV, WO, out);
    else          na_body<false>(sm, hX, hE, mask, WQ, WK, WV, WO, out);
}

extern "C" void kernel_launch(void* const* d_in, const int* in_sizes, int n_in,
                              void* d_out, int out_size, void* d_ws, size_t ws_size,
                              hipStream_t stream) {
    (void)in_sizes; (void)n_in; (void)ws_size; (void)out_size; (void)d_ws;
    const void* hX   = d_in[0];
    const void* hE   = d_in[1];
    const int*  mask = (const int*)d_in[2];
    const void* WQ   = d_in[3];
    const void* WK   = d_in[4];
    const void* WV   = d_in[5];
    const void* WO   = d_in[6];

    na_fused<<<dim3(1024), dim3(256), 0, stream>>>(hX, hE, mask, WQ, WK, WV, WO, d_out);
}